// Round 3
// baseline (7514.184 us; speedup 1.0000x reference)
//
#include <hip/hip_runtime.h>

// LightGCN forward on MI355X — round 3: coarse bucket binning + LDS-accumulate SpMM.
// Round-2 evidence: row-exact CSR scatter = 555 us with 395 MB WRITE_SIZE (8x write
// amplification from random 8B stores). Fix: single radix pass into 1172 buckets of
// 128 rows (runs merge in L2 write-back), SpMM accumulates per-bucket in 32 KB LDS
// via ds_add_f32; row packed into the pair word so no row_ptr/counts needed.

#define N_USERS  100000
#define N_ITEMS  50000
#define N_TOTAL  150000          // N_USERS + N_ITEMS
#define D        64
#define NNZ      6400000
#define BATCH    4096
#define NELEM    (N_TOTAL * D)   // 9,600,000
#define RPB      128                          // rows per bucket (row >> 7)
#define NBUK     ((N_TOTAL + RPB - 1) / RPB)  // 1172
#define CHUNK    8192
#define EB       ((NNZ + CHUNK - 1) / CHUNK)  // 782

// ---------- init: acc = cur = concat(user,item); zero bucket counts ----------
__global__ void lgcn_init(const float* __restrict__ user_emb,
                          const float* __restrict__ item_emb,
                          float* __restrict__ acc,
                          float* __restrict__ cur,
                          int*   __restrict__ bucket_cnt) {
    int i = blockIdx.x * blockDim.x + threadIdx.x;
    if (i < NELEM) {
        float v = (i < N_USERS * D) ? user_emb[i] : item_emb[i - N_USERS * D];
        acc[i] = v;
        cur[i] = v;
    }
    if (i < NBUK) bucket_cnt[i] = 0;
}

// ---------- pass A: per-bucket edge counts (LDS-aggregated) ----------
__global__ void lgcn_bucket_count(const int* __restrict__ rows,
                                  int* __restrict__ bucket_cnt) {
    __shared__ int lh[NBUK];
    for (int i = threadIdx.x; i < NBUK; i += 256) lh[i] = 0;
    __syncthreads();
    int s = blockIdx.x * CHUNK;
    int e_end = s + CHUNK; if (e_end > NNZ) e_end = NNZ;
    for (int e = s + threadIdx.x; e < e_end; e += 256)
        atomicAdd(&lh[rows[e] >> 7], 1);
    __syncthreads();
    for (int i = threadIdx.x; i < NBUK; i += 256)
        if (lh[i]) atomicAdd(&bucket_cnt[i], lh[i]);
}

// ---------- exclusive scan of 1172 bucket counts, one block ----------
__global__ void lgcn_bucket_scan(const int* __restrict__ cnt,
                                 int* __restrict__ ptr,
                                 int* __restrict__ cursor) {
    __shared__ int s[1024];
    int t = threadIdx.x;
    int i0 = 2 * t, i1 = 2 * t + 1;
    int c0 = (i0 < NBUK) ? cnt[i0] : 0;
    int c1 = (i1 < NBUK) ? cnt[i1] : 0;
    int v = c0 + c1;
    s[t] = v;
    __syncthreads();
    for (int off = 1; off < 1024; off <<= 1) {
        int u = (t >= off) ? s[t - off] : 0;
        __syncthreads();
        s[t] += u;
        __syncthreads();
    }
    int excl = s[t] - v;
    if (i0 < NBUK) { ptr[i0] = excl;      cursor[i0] = excl; }
    if (i1 < NBUK) { ptr[i1] = excl + c0; cursor[i1] = excl + c0; }
}

// ---------- pass B: scatter edges into bucket order ----------
// pair.x = (local_row<<18) | col   (col < 2^18, local_row < 128)
__global__ void lgcn_bucket_scatter(const int*   __restrict__ rows,
                                    const int*   __restrict__ cols,
                                    const float* __restrict__ vals,
                                    int*         __restrict__ cursor,
                                    int2*        __restrict__ pairs) {
    __shared__ int lhist[NBUK];
    __shared__ int lbase[NBUK];
    for (int i = threadIdx.x; i < NBUK; i += 256) lhist[i] = 0;
    __syncthreads();
    int s = blockIdx.x * CHUNK;
    int e_end = s + CHUNK; if (e_end > NNZ) e_end = NNZ;
    for (int e = s + threadIdx.x; e < e_end; e += 256)
        atomicAdd(&lhist[rows[e] >> 7], 1);
    __syncthreads();
    for (int i = threadIdx.x; i < NBUK; i += 256) {
        int c = lhist[i];
        lbase[i] = c ? atomicAdd(&cursor[i], c) : 0;
    }
    __syncthreads();
    for (int i = threadIdx.x; i < NBUK; i += 256) lhist[i] = 0;  // reuse as local cursor
    __syncthreads();
    for (int e = s + threadIdx.x; e < e_end; e += 256) {
        int r = rows[e];
        int bk = r >> 7;
        int rank = atomicAdd(&lhist[bk], 1);
        int2 p;
        p.x = ((r & 127) << 18) | cols[e];
        p.y = __float_as_int(vals[e]);
        pairs[lbase[bk] + rank] = p;     // runs merge in L2 write-back
    }
}

// ---------- SpMM: one block per bucket, 128x64 f32 accumulator in LDS ----------
__global__ void __launch_bounds__(256)
lgcn_spmm_bucket(const int2* __restrict__ pairs,
                 const int*  __restrict__ bptr,
                 const int*  __restrict__ bcnt,
                 const float* __restrict__ cur,
                 float* __restrict__ nxt,
                 float* __restrict__ acc,
                 int write_nxt) {
    __shared__ float lacc[RPB * D];   // 32 KB -> 5 blocks/CU
    int tid = threadIdx.x;
    for (int i = tid; i < RPB * D; i += 256) lacc[i] = 0.0f;
    __syncthreads();

    int b = blockIdx.x;
    int start = bptr[b];
    int cnt   = bcnt[b];
    int lane  = tid & 63;

    for (int base = (tid >> 6) * 64; base < cnt; base += 256) {
        int idx = base + lane;
        int2 p = {0, 0};
        if (idx < cnt) p = pairs[start + idx];   // coalesced dwordx2
        int m = cnt - base; if (m > 64) m = 64;
        int j = 0;
        for (; j + 4 <= m; j += 4) {             // 4 outstanding gathers
            int x0 = __shfl(p.x, j,     64);
            int x1 = __shfl(p.x, j + 1, 64);
            int x2 = __shfl(p.x, j + 2, 64);
            int x3 = __shfl(p.x, j + 3, 64);
            float v0 = __int_as_float(__shfl(p.y, j,     64));
            float v1 = __int_as_float(__shfl(p.y, j + 1, 64));
            float v2 = __int_as_float(__shfl(p.y, j + 2, 64));
            float v3 = __int_as_float(__shfl(p.y, j + 3, 64));
            float g0 = cur[(x0 & 0x3FFFF) * D + lane];
            float g1 = cur[(x1 & 0x3FFFF) * D + lane];
            float g2 = cur[(x2 & 0x3FFFF) * D + lane];
            float g3 = cur[(x3 & 0x3FFFF) * D + lane];
            atomicAdd(&lacc[((x0 >> 18) << 6) + lane], v0 * g0);  // ds_add_f32
            atomicAdd(&lacc[((x1 >> 18) << 6) + lane], v1 * g1);
            atomicAdd(&lacc[((x2 >> 18) << 6) + lane], v2 * g2);
            atomicAdd(&lacc[((x3 >> 18) << 6) + lane], v3 * g3);
        }
        for (; j < m; j++) {
            int   x = __shfl(p.x, j, 64);
            float v = __int_as_float(__shfl(p.y, j, 64));
            float g = cur[(x & 0x3FFFF) * D + lane];
            atomicAdd(&lacc[((x >> 18) << 6) + lane], v * g);
        }
    }
    __syncthreads();

    long long fb = (long long)b * (RPB * D);
    for (int i = tid; i < RPB * D; i += 256) {
        long long g = fb + i;
        if (g < NELEM) {
            float sv = lacc[i];
            if (write_nxt) nxt[g] = sv;
            acc[g] += sv;
        }
    }
}

// ---------- epilogue dot ----------
__global__ void lgcn_dot(const float* __restrict__ acc,
                         const int* __restrict__ users,
                         const int* __restrict__ items,
                         float* __restrict__ out) {
    int t = blockIdx.x * blockDim.x + threadIdx.x;
    int b = t >> 6;
    int d = t & 63;
    if (b < BATCH) {
        int u  = users[b];
        int it = items[b];
        float p = acc[u * D + d] * acc[(N_USERS + it) * D + d];
        #pragma unroll
        for (int off = 32; off; off >>= 1) p += __shfl_down(p, off, 64);
        if (d == 0) out[b] = p * (1.0f / 16.0f);
    }
}

// ---------- round-1 fallback (atomic scatter) if ws too small ----------
__global__ void lgcn_init_fb(const float* __restrict__ user_emb,
                             const float* __restrict__ item_emb,
                             float* __restrict__ acc,
                             float* __restrict__ cur,
                             float* __restrict__ nxt) {
    int i = blockIdx.x * blockDim.x + threadIdx.x;
    if (i < NELEM) {
        float v = (i < N_USERS * D) ? user_emb[i] : item_emb[i - N_USERS * D];
        acc[i] = v; cur[i] = v; nxt[i] = 0.0f;
    }
}
__global__ void lgcn_spmm_fb(const int* __restrict__ rows,
                             const int* __restrict__ cols,
                             const float* __restrict__ vals,
                             const float* __restrict__ cur,
                             float* __restrict__ nxt) {
    long long t = (long long)blockIdx.x * blockDim.x + threadIdx.x;
    int e = (int)(t >> 6);
    int d = (int)(t & 63);
    if (e < NNZ) {
        float x = cur[cols[e] * D + d];
        unsafeAtomicAdd(&nxt[rows[e] * D + d], vals[e] * x);
    }
}
__global__ void lgcn_accum_fb(float* __restrict__ acc,
                              const float* __restrict__ src,
                              float* __restrict__ to_zero) {
    int i = blockIdx.x * blockDim.x + threadIdx.x;
    if (i < NELEM) {
        acc[i] += src[i];
        if (to_zero) to_zero[i] = 0.0f;
    }
}

extern "C" void kernel_launch(void* const* d_in, const int* in_sizes, int n_in,
                              void* d_out, int out_size, void* d_ws, size_t ws_size,
                              hipStream_t stream) {
    const float* user_emb = (const float*)d_in[0];
    const float* item_emb = (const float*)d_in[1];
    const int*   edge_row = (const int*)d_in[2];
    const int*   edge_col = (const int*)d_in[3];
    const float* edge_val = (const float*)d_in[4];
    const int*   users    = (const int*)d_in[5];
    const int*   items    = (const int*)d_in[6];
    float*       out      = (float*)d_out;

    const int TPB = 256;
    int init_blocks = (NELEM + TPB - 1) / TPB;
    int dot_blocks  = (BATCH * 64 + TPB - 1) / TPB;

    // workspace layout
    float* acc = (float*)d_ws;                 // NELEM
    float* A   = acc + NELEM;                  // NELEM
    float* B   = A + NELEM;                    // NELEM
    int2*  pairs      = (int2*)(B + NELEM);    // NNZ int2
    int*   bucket_cnt = (int*)(pairs + NNZ);   // NBUK
    int*   bucket_ptr = bucket_cnt + NBUK;     // NBUK
    int*   cursor     = bucket_ptr + NBUK;     // NBUK
    size_t req = (size_t)((char*)(cursor + NBUK) - (char*)d_ws);

    if (ws_size < req) {
        // fallback: round-1 atomic path (needs only 3*NELEM floats)
        long long st = (long long)NNZ * 64;
        int sb = (int)((st + TPB - 1) / TPB);
        lgcn_init_fb<<<init_blocks, TPB, 0, stream>>>(user_emb, item_emb, acc, A, B);
        lgcn_spmm_fb<<<sb, TPB, 0, stream>>>(edge_row, edge_col, edge_val, A, B);
        lgcn_accum_fb<<<init_blocks, TPB, 0, stream>>>(acc, B, A);
        lgcn_spmm_fb<<<sb, TPB, 0, stream>>>(edge_row, edge_col, edge_val, B, A);
        lgcn_accum_fb<<<init_blocks, TPB, 0, stream>>>(acc, A, B);
        lgcn_spmm_fb<<<sb, TPB, 0, stream>>>(edge_row, edge_col, edge_val, A, B);
        lgcn_accum_fb<<<init_blocks, TPB, 0, stream>>>(acc, B, nullptr);
        lgcn_dot<<<dot_blocks, TPB, 0, stream>>>(acc, users, items, out);
        return;
    }

    // init embeddings + zero bucket histogram
    lgcn_init<<<init_blocks, TPB, 0, stream>>>(user_emb, item_emb, acc, A, bucket_cnt);

    // bucket binning: count -> scan -> scatter
    lgcn_bucket_count<<<EB, TPB, 0, stream>>>(edge_row, bucket_cnt);
    lgcn_bucket_scan<<<1, 1024, 0, stream>>>(bucket_cnt, bucket_ptr, cursor);
    lgcn_bucket_scatter<<<EB, TPB, 0, stream>>>(edge_row, edge_col, edge_val, cursor, pairs);

    // 3 propagation layers, acc += fused; skip nxt store on the last
    lgcn_spmm_bucket<<<NBUK, TPB, 0, stream>>>(pairs, bucket_ptr, bucket_cnt, A, B, acc, 1);
    lgcn_spmm_bucket<<<NBUK, TPB, 0, stream>>>(pairs, bucket_ptr, bucket_cnt, B, A, acc, 1);
    lgcn_spmm_bucket<<<NBUK, TPB, 0, stream>>>(pairs, bucket_ptr, bucket_cnt, A, B, acc, 0);

    // gamma
    lgcn_dot<<<dot_blocks, TPB, 0, stream>>>(acc, users, items, out);
}

// Round 4
// 866.553 us; speedup vs baseline: 8.6714x; 8.6714x over previous
//
#include <hip/hip_runtime.h>

// LightGCN forward on MI355X — round 4.
// r2 evidence: wave-per-row register SpMM fast (~300us/layer); row-exact global
//   scatter slow (555us, 8x write amplification).
// r3 evidence: coarse bucket binning cheap (~250us total) but bucket-SpMM with LDS
//   atomics latency-starved (4688 waves, occ 34%, 2405us).
// r4: coarse binning + in-LDS per-bucket exact sort (random writes confined to a
//   44KB L2-resident window) -> exact CSR -> r2's wave-per-row SpMM. Layer 3
//   computed only at the 8192 sampled rows (gamma only reads those).

#define N_USERS  100000
#define N_ITEMS  50000
#define N_TOTAL  150000          // N_USERS + N_ITEMS
#define D        64
#define NNZ      6400000
#define BATCH    4096
#define NELEM    (N_TOTAL * D)   // 9,600,000
#define RPB      128                          // rows per bucket (row >> 7)
#define NBUK     ((N_TOTAL + RPB - 1) / RPB)  // 1172
#define NROWPAD  (NBUK * RPB)                 // 150016
#define CHUNK    8192
#define EB       ((NNZ + CHUNK - 1) / CHUNK)  // 782
#define SORTCAP  8192            // bucket mean 5461, sigma 74 -> +37 sigma headroom

// ---------- init: acc = cur = concat(user,item); zero bucket counts ----------
__global__ void lgcn_init(const float* __restrict__ user_emb,
                          const float* __restrict__ item_emb,
                          float* __restrict__ acc,
                          float* __restrict__ cur,
                          int*   __restrict__ bucket_cnt) {
    int i = blockIdx.x * blockDim.x + threadIdx.x;
    if (i < NELEM) {
        float v = (i < N_USERS * D) ? user_emb[i] : item_emb[i - N_USERS * D];
        acc[i] = v;
        cur[i] = v;
    }
    if (i < NBUK) bucket_cnt[i] = 0;
}

// ---------- pass A: per-bucket edge counts (LDS-aggregated) ----------
__global__ void lgcn_bucket_count(const int* __restrict__ rows,
                                  int* __restrict__ bucket_cnt) {
    __shared__ int lh[NBUK];
    for (int i = threadIdx.x; i < NBUK; i += 256) lh[i] = 0;
    __syncthreads();
    int s = blockIdx.x * CHUNK;
    int e_end = s + CHUNK; if (e_end > NNZ) e_end = NNZ;
    for (int e = s + threadIdx.x; e < e_end; e += 256)
        atomicAdd(&lh[rows[e] >> 7], 1);
    __syncthreads();
    for (int i = threadIdx.x; i < NBUK; i += 256)
        if (lh[i]) atomicAdd(&bucket_cnt[i], lh[i]);
}

// ---------- exclusive scan of 1172 bucket counts, one block ----------
__global__ void lgcn_bucket_scan(const int* __restrict__ cnt,
                                 int* __restrict__ ptr,
                                 int* __restrict__ cursor) {
    __shared__ int s[1024];
    int t = threadIdx.x;
    int i0 = 2 * t, i1 = 2 * t + 1;
    int c0 = (i0 < NBUK) ? cnt[i0] : 0;
    int c1 = (i1 < NBUK) ? cnt[i1] : 0;
    int v = c0 + c1;
    s[t] = v;
    __syncthreads();
    for (int off = 1; off < 1024; off <<= 1) {
        int u = (t >= off) ? s[t - off] : 0;
        __syncthreads();
        s[t] += u;
        __syncthreads();
    }
    int excl = s[t] - v;
    if (i0 < NBUK) { ptr[i0] = excl;      cursor[i0] = excl; }
    if (i1 < NBUK) { ptr[i1] = excl + c0; cursor[i1] = excl + c0; }
}

// ---------- pass B: scatter edges into bucket order ----------
// pair.x = (local_row<<18) | col   (col < 2^18, local_row < 128)
__global__ void lgcn_bucket_scatter(const int*   __restrict__ rows,
                                    const int*   __restrict__ cols,
                                    const float* __restrict__ vals,
                                    int*         __restrict__ cursor,
                                    int2*        __restrict__ pairs) {
    __shared__ int lhist[NBUK];
    __shared__ int lbase[NBUK];
    for (int i = threadIdx.x; i < NBUK; i += 256) lhist[i] = 0;
    __syncthreads();
    int s = blockIdx.x * CHUNK;
    int e_end = s + CHUNK; if (e_end > NNZ) e_end = NNZ;
    for (int e = s + threadIdx.x; e < e_end; e += 256)
        atomicAdd(&lhist[rows[e] >> 7], 1);
    __syncthreads();
    for (int i = threadIdx.x; i < NBUK; i += 256) {
        int c = lhist[i];
        lbase[i] = c ? atomicAdd(&cursor[i], c) : 0;
    }
    __syncthreads();
    for (int i = threadIdx.x; i < NBUK; i += 256) lhist[i] = 0;  // reuse as local cursor
    __syncthreads();
    for (int e = s + threadIdx.x; e < e_end; e += 256) {
        int r = rows[e];
        int bk = r >> 7;
        int rank = atomicAdd(&lhist[bk], 1);
        int2 p;
        p.x = ((r & 127) << 18) | cols[e];
        p.y = __float_as_int(vals[e]);
        pairs[lbase[bk] + rank] = p;     // short runs, merge in L2 write-back
    }
}

// ---------- pass C: in-LDS exact sort within each bucket; emit row_ptr/row_cnt ----
__global__ void __launch_bounds__(256)
lgcn_bucket_sort(int2* __restrict__ pairs,
                 const int* __restrict__ bptr,
                 const int* __restrict__ bcnt,
                 int* __restrict__ row_ptr,
                 int* __restrict__ row_cnt) {
    __shared__ int2 buf[SORTCAP];      // 64 KB
    __shared__ int  h[RPB];
    __shared__ int  base[RPB];
    int tid = threadIdx.x;
    int b = blockIdx.x;
    int start = bptr[b];
    int cnt   = bcnt[b];
    if (cnt > SORTCAP) cnt = SORTCAP;  // unreachable for this data; safety only

    for (int i = tid; i < cnt; i += 256) buf[i] = pairs[start + i];
    for (int i = tid; i < RPB; i += 256) h[i] = 0;
    __syncthreads();
    for (int i = tid; i < cnt; i += 256) atomicAdd(&h[buf[i].x >> 18], 1);
    __syncthreads();

    // exclusive scan of h[0..127] (Hillis-Steele, all threads hit barriers)
    int v = (tid < RPB) ? h[tid] : 0;
    int sum = v;
    #pragma unroll
    for (int off = 1; off < RPB; off <<= 1) {
        int u = (tid >= off && tid < RPB) ? base[0] : 0;  // placeholder, see below
        (void)u;
        // standard LDS scan using base[] as scratch
        if (tid < RPB) base[tid] = sum;
        __syncthreads();
        if (tid >= off && tid < RPB) sum += base[tid - off];
        __syncthreads();
    }
    // sum = inclusive scan of h; exclusive = sum - v
    if (tid < RPB) {
        int excl = sum - v;
        base[tid] = excl;
        int gr = b * RPB + tid;
        if (gr < N_TOTAL) {
            row_ptr[gr] = start + excl;
            row_cnt[gr] = v;
        }
        h[tid] = 0;                    // reuse as per-row cursor
    }
    __syncthreads();

    for (int i = tid; i < cnt; i += 256) {
        int2 p = buf[i];
        int lr = p.x >> 18;
        int rank = atomicAdd(&h[lr], 1);
        pairs[start + base[lr] + rank] = p;   // random within 44KB window -> L2
    }
}

// ---------- SpMM: one wave per row, lane = dim, register accumulate ----------
// nxt[r,:] = sum_e val_e * cur[col_e,:];  acc[r,:] += nxt[r,:]
__global__ void lgcn_spmm_csr(const int2* __restrict__ pairs,
                              const int*  __restrict__ row_ptr,
                              const int*  __restrict__ row_cnt,
                              const float* __restrict__ cur,
                              float* __restrict__ nxt,
                              float* __restrict__ acc) {
    int t = blockIdx.x * blockDim.x + threadIdx.x;
    int r = t >> 6;
    int lane = t & 63;
    if (r >= N_TOTAL) return;
    int start = row_ptr[r];
    int cnt   = row_cnt[r];
    float sum0 = 0.f, sum1 = 0.f;
    for (int base = 0; base < cnt; base += 64) {
        int idx = base + lane;
        int2 p = {0, 0};
        if (idx < cnt) p = pairs[start + idx];     // coalesced dwordx2
        int m = cnt - base; if (m > 64) m = 64;
        int j = 0;
        for (; j + 4 <= m; j += 4) {               // 4 outstanding gathers
            int   c0 = __shfl(p.x, j,     64);
            int   c1 = __shfl(p.x, j + 1, 64);
            int   c2 = __shfl(p.x, j + 2, 64);
            int   c3 = __shfl(p.x, j + 3, 64);
            float v0 = __int_as_float(__shfl(p.y, j,     64));
            float v1 = __int_as_float(__shfl(p.y, j + 1, 64));
            float v2 = __int_as_float(__shfl(p.y, j + 2, 64));
            float v3 = __int_as_float(__shfl(p.y, j + 3, 64));
            float x0 = cur[(c0 & 0x3FFFF) * D + lane];
            float x1 = cur[(c1 & 0x3FFFF) * D + lane];
            float x2 = cur[(c2 & 0x3FFFF) * D + lane];
            float x3 = cur[(c3 & 0x3FFFF) * D + lane];
            sum0 += v0 * x0;
            sum1 += v1 * x1;
            sum0 += v2 * x2;
            sum1 += v3 * x3;
        }
        for (; j < m; j++) {
            int   c = __shfl(p.x, j, 64);
            float v = __int_as_float(__shfl(p.y, j, 64));
            sum0 += v * cur[(c & 0x3FFFF) * D + lane];
        }
    }
    float sum = sum0 + sum1;
    int o = r * D + lane;
    nxt[o] = sum;
    acc[o] += sum;
}

// ---------- layer 3, sampled rows only: e3[s,:] = (A @ E2)[row(s),:] ----------
__global__ void lgcn_spmm_sampled(const int2* __restrict__ pairs,
                                  const int*  __restrict__ row_ptr,
                                  const int*  __restrict__ row_cnt,
                                  const float* __restrict__ cur,
                                  const int* __restrict__ users,
                                  const int* __restrict__ items,
                                  float* __restrict__ e3) {
    int t = blockIdx.x * blockDim.x + threadIdx.x;
    int s = t >> 6;
    int lane = t & 63;
    if (s >= 2 * BATCH) return;
    int r = (s < BATCH) ? users[s] : (N_USERS + items[s - BATCH]);
    int start = row_ptr[r];
    int cnt   = row_cnt[r];
    float sum0 = 0.f, sum1 = 0.f;
    for (int base = 0; base < cnt; base += 64) {
        int idx = base + lane;
        int2 p = {0, 0};
        if (idx < cnt) p = pairs[start + idx];
        int m = cnt - base; if (m > 64) m = 64;
        int j = 0;
        for (; j + 4 <= m; j += 4) {
            int   c0 = __shfl(p.x, j,     64);
            int   c1 = __shfl(p.x, j + 1, 64);
            int   c2 = __shfl(p.x, j + 2, 64);
            int   c3 = __shfl(p.x, j + 3, 64);
            float v0 = __int_as_float(__shfl(p.y, j,     64));
            float v1 = __int_as_float(__shfl(p.y, j + 1, 64));
            float v2 = __int_as_float(__shfl(p.y, j + 2, 64));
            float v3 = __int_as_float(__shfl(p.y, j + 3, 64));
            sum0 += v0 * cur[(c0 & 0x3FFFF) * D + lane];
            sum1 += v1 * cur[(c1 & 0x3FFFF) * D + lane];
            sum0 += v2 * cur[(c2 & 0x3FFFF) * D + lane];
            sum1 += v3 * cur[(c3 & 0x3FFFF) * D + lane];
        }
        for (; j < m; j++) {
            int   c = __shfl(p.x, j, 64);
            float v = __int_as_float(__shfl(p.y, j, 64));
            sum0 += v * cur[(c & 0x3FFFF) * D + lane];
        }
    }
    e3[s * D + lane] = sum0 + sum1;
}

// ---------- epilogue dot: gamma = (acc2_u + e3_u).(acc2_i + e3_i) / 16 ----------
__global__ void lgcn_dot(const float* __restrict__ acc,
                         const float* __restrict__ e3,
                         const int* __restrict__ users,
                         const int* __restrict__ items,
                         float* __restrict__ out) {
    int t = blockIdx.x * blockDim.x + threadIdx.x;
    int b = t >> 6;
    int d = t & 63;
    if (b < BATCH) {
        int u  = users[b];
        int it = items[b];
        float au = acc[u * D + d] + e3[b * D + d];
        float ai = acc[(N_USERS + it) * D + d] + e3[(BATCH + b) * D + d];
        float p = au * ai;
        #pragma unroll
        for (int off = 32; off; off >>= 1) p += __shfl_down(p, off, 64);
        if (d == 0) out[b] = p * (1.0f / 16.0f);
    }
}

// ---------- round-1 fallback (atomic scatter) if ws too small ----------
__global__ void lgcn_init_fb(const float* __restrict__ user_emb,
                             const float* __restrict__ item_emb,
                             float* __restrict__ acc,
                             float* __restrict__ cur,
                             float* __restrict__ nxt) {
    int i = blockIdx.x * blockDim.x + threadIdx.x;
    if (i < NELEM) {
        float v = (i < N_USERS * D) ? user_emb[i] : item_emb[i - N_USERS * D];
        acc[i] = v; cur[i] = v; nxt[i] = 0.0f;
    }
}
__global__ void lgcn_spmm_fb(const int* __restrict__ rows,
                             const int* __restrict__ cols,
                             const float* __restrict__ vals,
                             const float* __restrict__ cur,
                             float* __restrict__ nxt) {
    long long t = (long long)blockIdx.x * blockDim.x + threadIdx.x;
    int e = (int)(t >> 6);
    int d = (int)(t & 63);
    if (e < NNZ) {
        float x = cur[cols[e] * D + d];
        unsafeAtomicAdd(&nxt[rows[e] * D + d], vals[e] * x);
    }
}
__global__ void lgcn_accum_fb(float* __restrict__ acc,
                              const float* __restrict__ src,
                              float* __restrict__ to_zero) {
    int i = blockIdx.x * blockDim.x + threadIdx.x;
    if (i < NELEM) {
        acc[i] += src[i];
        if (to_zero) to_zero[i] = 0.0f;
    }
}
__global__ void lgcn_dot_fb(const float* __restrict__ acc,
                            const int* __restrict__ users,
                            const int* __restrict__ items,
                            float* __restrict__ out) {
    int t = blockIdx.x * blockDim.x + threadIdx.x;
    int b = t >> 6;
    int d = t & 63;
    if (b < BATCH) {
        int u  = users[b];
        int it = items[b];
        float p = acc[u * D + d] * acc[(N_USERS + it) * D + d];
        #pragma unroll
        for (int off = 32; off; off >>= 1) p += __shfl_down(p, off, 64);
        if (d == 0) out[b] = p * (1.0f / 16.0f);
    }
}

extern "C" void kernel_launch(void* const* d_in, const int* in_sizes, int n_in,
                              void* d_out, int out_size, void* d_ws, size_t ws_size,
                              hipStream_t stream) {
    const float* user_emb = (const float*)d_in[0];
    const float* item_emb = (const float*)d_in[1];
    const int*   edge_row = (const int*)d_in[2];
    const int*   edge_col = (const int*)d_in[3];
    const float* edge_val = (const float*)d_in[4];
    const int*   users    = (const int*)d_in[5];
    const int*   items    = (const int*)d_in[6];
    float*       out      = (float*)d_out;

    const int TPB = 256;
    int init_blocks = (NELEM + TPB - 1) / TPB;
    int spmm_blocks = (N_TOTAL * 64 + TPB - 1) / TPB;       // wave per row
    int samp_blocks = (2 * BATCH * 64 + TPB - 1) / TPB;     // wave per sampled row
    int dot_blocks  = (BATCH * 64 + TPB - 1) / TPB;

    // workspace layout
    float* acc = (float*)d_ws;                 // NELEM
    float* A   = acc + NELEM;                  // NELEM
    float* B   = A + NELEM;                    // NELEM
    float* e3  = B + NELEM;                    // 2*BATCH*D = 524288
    int2*  pairs      = (int2*)(e3 + 2 * BATCH * D);  // NNZ
    int*   bucket_cnt = (int*)(pairs + NNZ);   // NBUK
    int*   bucket_ptr = bucket_cnt + NBUK;     // NBUK
    int*   cursor     = bucket_ptr + NBUK;     // NBUK
    int*   row_ptr    = cursor + NBUK;         // NROWPAD
    int*   row_cnt    = row_ptr + NROWPAD;     // NROWPAD
    size_t req = (size_t)((char*)(row_cnt + NROWPAD) - (char*)d_ws);

    if (ws_size < req) {
        // fallback: round-1 atomic path (needs only 3*NELEM floats)
        long long st = (long long)NNZ * 64;
        int sb = (int)((st + TPB - 1) / TPB);
        lgcn_init_fb<<<init_blocks, TPB, 0, stream>>>(user_emb, item_emb, acc, A, B);
        lgcn_spmm_fb<<<sb, TPB, 0, stream>>>(edge_row, edge_col, edge_val, A, B);
        lgcn_accum_fb<<<init_blocks, TPB, 0, stream>>>(acc, B, A);
        lgcn_spmm_fb<<<sb, TPB, 0, stream>>>(edge_row, edge_col, edge_val, B, A);
        lgcn_accum_fb<<<init_blocks, TPB, 0, stream>>>(acc, A, B);
        lgcn_spmm_fb<<<sb, TPB, 0, stream>>>(edge_row, edge_col, edge_val, A, B);
        lgcn_accum_fb<<<init_blocks, TPB, 0, stream>>>(acc, B, nullptr);
        lgcn_dot_fb<<<dot_blocks, TPB, 0, stream>>>(acc, users, items, out);
        return;
    }

    // init embeddings + zero bucket histogram
    lgcn_init<<<init_blocks, TPB, 0, stream>>>(user_emb, item_emb, acc, A, bucket_cnt);

    // binning: count -> scan -> coarse scatter -> in-LDS exact sort (emits CSR)
    lgcn_bucket_count<<<EB, TPB, 0, stream>>>(edge_row, bucket_cnt);
    lgcn_bucket_scan<<<1, 1024, 0, stream>>>(bucket_cnt, bucket_ptr, cursor);
    lgcn_bucket_scatter<<<EB, TPB, 0, stream>>>(edge_row, edge_col, edge_val, cursor, pairs);
    lgcn_bucket_sort<<<NBUK, TPB, 0, stream>>>(pairs, bucket_ptr, bucket_cnt, row_ptr, row_cnt);

    // layers 1,2 full; layer 3 only at sampled rows
    lgcn_spmm_csr<<<spmm_blocks, TPB, 0, stream>>>(pairs, row_ptr, row_cnt, A, B, acc);
    lgcn_spmm_csr<<<spmm_blocks, TPB, 0, stream>>>(pairs, row_ptr, row_cnt, B, A, acc);
    lgcn_spmm_sampled<<<samp_blocks, TPB, 0, stream>>>(pairs, row_ptr, row_cnt, A,
                                                       users, items, e3);

    // gamma
    lgcn_dot<<<dot_blocks, TPB, 0, stream>>>(acc, e3, users, items, out);
}

// Round 5
// 690.703 us; speedup vs baseline: 10.8790x; 1.2546x over previous
//
#include <hip/hip_runtime.h>
#include <hip/hip_bf16.h>

// LightGCN forward on MI355X — round 5.
// r4 evidence: spmm_csr gather-bound (790MB L2-miss/layer, VALU 25%); acc buffer
//   only ever read at 8192 sampled rows. r5: (1) drop acc — dot sums
//   E0(inputs)+E1+E2+E3 at sampled rows; (2) layer inputs stored bf16 (RNE) ->
//   gathers 128B/wave instead of 256B; (3) 8-deep gather unroll; (4) scatter
//   CHUNK 16384 (longer per-bucket runs -> less partial-sector write amp).

#define N_USERS  100000
#define N_ITEMS  50000
#define N_TOTAL  150000          // N_USERS + N_ITEMS
#define D        64
#define NNZ      6400000
#define BATCH    4096
#define NELEM    (N_TOTAL * D)   // 9,600,000
#define RPB      128                          // rows per bucket (row >> 7)
#define NBUK     ((N_TOTAL + RPB - 1) / RPB)  // 1172
#define NROWPAD  (NBUK * RPB)                 // 150016
#define CHUNK    16384
#define EB       ((NNZ + CHUNK - 1) / CHUNK)  // 391
#define SORTCAP  8192            // bucket mean 5461, sigma 74 -> +37 sigma headroom

__device__ __forceinline__ float bf2f(unsigned short h) {
    return __uint_as_float(((unsigned int)h) << 16);
}

// ---------- init: A = bf16(concat(user,item)); zero bucket counts ----------
__global__ void lgcn_init(const float* __restrict__ user_emb,
                          const float* __restrict__ item_emb,
                          unsigned short* __restrict__ A,
                          int* __restrict__ bucket_cnt) {
    int i = blockIdx.x * blockDim.x + threadIdx.x;
    if (i < NELEM) {
        float v = (i < N_USERS * D) ? user_emb[i] : item_emb[i - N_USERS * D];
        __hip_bfloat16 b = __float2bfloat16(v);   // RNE
        A[i] = *(unsigned short*)&b;
    }
    if (i < NBUK) bucket_cnt[i] = 0;
}

// ---------- pass A: per-bucket edge counts (LDS-aggregated) ----------
__global__ void lgcn_bucket_count(const int* __restrict__ rows,
                                  int* __restrict__ bucket_cnt) {
    __shared__ int lh[NBUK];
    for (int i = threadIdx.x; i < NBUK; i += 256) lh[i] = 0;
    __syncthreads();
    int s = blockIdx.x * CHUNK;
    int e_end = s + CHUNK; if (e_end > NNZ) e_end = NNZ;
    for (int e = s + threadIdx.x; e < e_end; e += 256)
        atomicAdd(&lh[rows[e] >> 7], 1);
    __syncthreads();
    for (int i = threadIdx.x; i < NBUK; i += 256)
        if (lh[i]) atomicAdd(&bucket_cnt[i], lh[i]);
}

// ---------- exclusive scan of 1172 bucket counts, one block ----------
__global__ void lgcn_bucket_scan(const int* __restrict__ cnt,
                                 int* __restrict__ ptr,
                                 int* __restrict__ cursor) {
    __shared__ int s[1024];
    int t = threadIdx.x;
    int i0 = 2 * t, i1 = 2 * t + 1;
    int c0 = (i0 < NBUK) ? cnt[i0] : 0;
    int c1 = (i1 < NBUK) ? cnt[i1] : 0;
    int v = c0 + c1;
    s[t] = v;
    __syncthreads();
    for (int off = 1; off < 1024; off <<= 1) {
        int u = (t >= off) ? s[t - off] : 0;
        __syncthreads();
        s[t] += u;
        __syncthreads();
    }
    int excl = s[t] - v;
    if (i0 < NBUK) { ptr[i0] = excl;      cursor[i0] = excl; }
    if (i1 < NBUK) { ptr[i1] = excl + c0; cursor[i1] = excl + c0; }
}

// ---------- pass B: scatter edges into bucket order ----------
// pair.x = (local_row<<18) | col   (col < 2^18, local_row < 128)
__global__ void lgcn_bucket_scatter(const int*   __restrict__ rows,
                                    const int*   __restrict__ cols,
                                    const float* __restrict__ vals,
                                    int*         __restrict__ cursor,
                                    int2*        __restrict__ pairs) {
    __shared__ int lhist[NBUK];
    __shared__ int lbase[NBUK];
    for (int i = threadIdx.x; i < NBUK; i += 256) lhist[i] = 0;
    __syncthreads();
    int s = blockIdx.x * CHUNK;
    int e_end = s + CHUNK; if (e_end > NNZ) e_end = NNZ;
    for (int e = s + threadIdx.x; e < e_end; e += 256)
        atomicAdd(&lhist[rows[e] >> 7], 1);
    __syncthreads();
    for (int i = threadIdx.x; i < NBUK; i += 256) {
        int c = lhist[i];
        lbase[i] = c ? atomicAdd(&cursor[i], c) : 0;
    }
    __syncthreads();
    for (int i = threadIdx.x; i < NBUK; i += 256) lhist[i] = 0;  // reuse as local cursor
    __syncthreads();
    for (int e = s + threadIdx.x; e < e_end; e += 256) {
        int r = rows[e];
        int bk = r >> 7;
        int rank = atomicAdd(&lhist[bk], 1);
        int2 p;
        p.x = ((r & 127) << 18) | cols[e];
        p.y = __float_as_int(vals[e]);
        pairs[lbase[bk] + rank] = p;     // ~14-edge runs, merge in L2 write-back
    }
}

// ---------- pass C: in-LDS exact sort within each bucket; emit row_ptr/row_cnt ----
__global__ void __launch_bounds__(256)
lgcn_bucket_sort(int2* __restrict__ pairs,
                 const int* __restrict__ bptr,
                 const int* __restrict__ bcnt,
                 int* __restrict__ row_ptr,
                 int* __restrict__ row_cnt) {
    __shared__ int2 buf[SORTCAP];      // 64 KB
    __shared__ int  h[RPB];
    __shared__ int  base[RPB];
    int tid = threadIdx.x;
    int b = blockIdx.x;
    int start = bptr[b];
    int cnt   = bcnt[b];
    if (cnt > SORTCAP) cnt = SORTCAP;  // unreachable for this data; safety only

    for (int i = tid; i < cnt; i += 256) buf[i] = pairs[start + i];
    for (int i = tid; i < RPB; i += 256) h[i] = 0;
    __syncthreads();
    for (int i = tid; i < cnt; i += 256) atomicAdd(&h[buf[i].x >> 18], 1);
    __syncthreads();

    // exclusive scan of h[0..127]
    int v = (tid < RPB) ? h[tid] : 0;
    int sum = v;
    #pragma unroll
    for (int off = 1; off < RPB; off <<= 1) {
        if (tid < RPB) base[tid] = sum;
        __syncthreads();
        if (tid >= off && tid < RPB) sum += base[tid - off];
        __syncthreads();
    }
    if (tid < RPB) {
        int excl = sum - v;
        base[tid] = excl;
        int gr = b * RPB + tid;
        if (gr < N_TOTAL) {
            row_ptr[gr] = start + excl;
            row_cnt[gr] = v;
        }
        h[tid] = 0;                    // reuse as per-row cursor
    }
    __syncthreads();

    for (int i = tid; i < cnt; i += 256) {
        int2 p = buf[i];
        int lr = p.x >> 18;
        int rank = atomicAdd(&h[lr], 1);
        pairs[start + base[lr] + rank] = p;   // random within 64KB window -> L2
    }
}

// ---------- SpMM: wave per row, bf16 gathers, bf16 output ----------
__global__ void lgcn_spmm_csr(const int2* __restrict__ pairs,
                              const int*  __restrict__ row_ptr,
                              const int*  __restrict__ row_cnt,
                              const unsigned short* __restrict__ cur,
                              unsigned short* __restrict__ nxt) {
    int t = blockIdx.x * blockDim.x + threadIdx.x;
    int r = t >> 6;
    int lane = t & 63;
    if (r >= N_TOTAL) return;
    int start = row_ptr[r];
    int cnt   = row_cnt[r];
    float sum0 = 0.f, sum1 = 0.f;
    for (int base = 0; base < cnt; base += 64) {
        int idx = base + lane;
        int2 p = {0, 0};
        if (idx < cnt) p = pairs[start + idx];     // coalesced dwordx2
        int m = cnt - base; if (m > 64) m = 64;
        int j = 0;
        for (; j + 8 <= m; j += 8) {               // 8 outstanding gathers
            float acc[8];
            #pragma unroll
            for (int k = 0; k < 8; k++) {
                int   c = __shfl(p.x, j + k, 64);
                float v = __int_as_float(__shfl(p.y, j + k, 64));
                acc[k] = v * bf2f(cur[(c & 0x3FFFF) * D + lane]);
            }
            sum0 += acc[0] + acc[2] + acc[4] + acc[6];
            sum1 += acc[1] + acc[3] + acc[5] + acc[7];
        }
        for (; j < m; j++) {
            int   c = __shfl(p.x, j, 64);
            float v = __int_as_float(__shfl(p.y, j, 64));
            sum0 += v * bf2f(cur[(c & 0x3FFFF) * D + lane]);
        }
    }
    __hip_bfloat16 o = __float2bfloat16(sum0 + sum1);   // RNE
    nxt[r * D + lane] = *(unsigned short*)&o;
}

// ---------- layer 3 at sampled rows only: e3[s,:] = (A @ E2)[row(s),:] (f32) ----
__global__ void lgcn_spmm_sampled(const int2* __restrict__ pairs,
                                  const int*  __restrict__ row_ptr,
                                  const int*  __restrict__ row_cnt,
                                  const unsigned short* __restrict__ cur,
                                  const int* __restrict__ users,
                                  const int* __restrict__ items,
                                  float* __restrict__ e3) {
    int t = blockIdx.x * blockDim.x + threadIdx.x;
    int s = t >> 6;
    int lane = t & 63;
    if (s >= 2 * BATCH) return;
    int r = (s < BATCH) ? users[s] : (N_USERS + items[s - BATCH]);
    int start = row_ptr[r];
    int cnt   = row_cnt[r];
    float sum0 = 0.f, sum1 = 0.f;
    for (int base = 0; base < cnt; base += 64) {
        int idx = base + lane;
        int2 p = {0, 0};
        if (idx < cnt) p = pairs[start + idx];
        int m = cnt - base; if (m > 64) m = 64;
        int j = 0;
        for (; j + 8 <= m; j += 8) {
            float acc[8];
            #pragma unroll
            for (int k = 0; k < 8; k++) {
                int   c = __shfl(p.x, j + k, 64);
                float v = __int_as_float(__shfl(p.y, j + k, 64));
                acc[k] = v * bf2f(cur[(c & 0x3FFFF) * D + lane]);
            }
            sum0 += acc[0] + acc[2] + acc[4] + acc[6];
            sum1 += acc[1] + acc[3] + acc[5] + acc[7];
        }
        for (; j < m; j++) {
            int   c = __shfl(p.x, j, 64);
            float v = __int_as_float(__shfl(p.y, j, 64));
            sum0 += v * bf2f(cur[(c & 0x3FFFF) * D + lane]);
        }
    }
    e3[s * D + lane] = sum0 + sum1;
}

// ---------- dot: gamma = <E0+E1+E2+E3>_u . <E0+E1+E2+E3>_i / 16 ----------
__global__ void lgcn_dot(const float* __restrict__ user_emb,
                         const float* __restrict__ item_emb,
                         const unsigned short* __restrict__ E1,
                         const unsigned short* __restrict__ E2,
                         const float* __restrict__ e3,
                         const int* __restrict__ users,
                         const int* __restrict__ items,
                         float* __restrict__ out) {
    int t = blockIdx.x * blockDim.x + threadIdx.x;
    int b = t >> 6;
    int d = t & 63;
    if (b < BATCH) {
        int u  = users[b];
        int it = items[b];
        int ur = u * D + d;
        int ir = (N_USERS + it) * D + d;
        float au = user_emb[ur] + bf2f(E1[ur]) + bf2f(E2[ur]) + e3[b * D + d];
        float ai = item_emb[it * D + d] + bf2f(E1[ir]) + bf2f(E2[ir])
                 + e3[(BATCH + b) * D + d];
        float p = au * ai;
        #pragma unroll
        for (int off = 32; off; off >>= 1) p += __shfl_down(p, off, 64);
        if (d == 0) out[b] = p * (1.0f / 16.0f);
    }
}

// ---------- round-1 fallback (atomic scatter) if ws too small ----------
__global__ void lgcn_init_fb(const float* __restrict__ user_emb,
                             const float* __restrict__ item_emb,
                             float* __restrict__ acc,
                             float* __restrict__ cur,
                             float* __restrict__ nxt) {
    int i = blockIdx.x * blockDim.x + threadIdx.x;
    if (i < NELEM) {
        float v = (i < N_USERS * D) ? user_emb[i] : item_emb[i - N_USERS * D];
        acc[i] = v; cur[i] = v; nxt[i] = 0.0f;
    }
}
__global__ void lgcn_spmm_fb(const int* __restrict__ rows,
                             const int* __restrict__ cols,
                             const float* __restrict__ vals,
                             const float* __restrict__ cur,
                             float* __restrict__ nxt) {
    long long t = (long long)blockIdx.x * blockDim.x + threadIdx.x;
    int e = (int)(t >> 6);
    int d = (int)(t & 63);
    if (e < NNZ) {
        float x = cur[cols[e] * D + d];
        unsafeAtomicAdd(&nxt[rows[e] * D + d], vals[e] * x);
    }
}
__global__ void lgcn_accum_fb(float* __restrict__ acc,
                              const float* __restrict__ src,
                              float* __restrict__ to_zero) {
    int i = blockIdx.x * blockDim.x + threadIdx.x;
    if (i < NELEM) {
        acc[i] += src[i];
        if (to_zero) to_zero[i] = 0.0f;
    }
}
__global__ void lgcn_dot_fb(const float* __restrict__ acc,
                            const int* __restrict__ users,
                            const int* __restrict__ items,
                            float* __restrict__ out) {
    int t = blockIdx.x * blockDim.x + threadIdx.x;
    int b = t >> 6;
    int d = t & 63;
    if (b < BATCH) {
        int u  = users[b];
        int it = items[b];
        float p = acc[u * D + d] * acc[(N_USERS + it) * D + d];
        #pragma unroll
        for (int off = 32; off; off >>= 1) p += __shfl_down(p, off, 64);
        if (d == 0) out[b] = p * (1.0f / 16.0f);
    }
}

extern "C" void kernel_launch(void* const* d_in, const int* in_sizes, int n_in,
                              void* d_out, int out_size, void* d_ws, size_t ws_size,
                              hipStream_t stream) {
    const float* user_emb = (const float*)d_in[0];
    const float* item_emb = (const float*)d_in[1];
    const int*   edge_row = (const int*)d_in[2];
    const int*   edge_col = (const int*)d_in[3];
    const float* edge_val = (const float*)d_in[4];
    const int*   users    = (const int*)d_in[5];
    const int*   items    = (const int*)d_in[6];
    float*       out      = (float*)d_out;

    const int TPB = 256;
    int init_blocks = (NELEM + TPB - 1) / TPB;
    int spmm_blocks = (N_TOTAL * 64 + TPB - 1) / TPB;       // wave per row
    int samp_blocks = (2 * BATCH * 64 + TPB - 1) / TPB;     // wave per sampled row
    int dot_blocks  = (BATCH * 64 + TPB - 1) / TPB;

    // workspace layout (bf16 layer buffers)
    unsigned short* A = (unsigned short*)d_ws;   // E0 bf16, NELEM
    unsigned short* B = A + NELEM;               // E1 bf16
    unsigned short* C = B + NELEM;               // E2 bf16
    float* e3 = (float*)(C + NELEM);             // 2*BATCH*D f32
    int2*  pairs      = (int2*)(e3 + 2 * BATCH * D);  // NNZ
    int*   bucket_cnt = (int*)(pairs + NNZ);     // NBUK
    int*   bucket_ptr = bucket_cnt + NBUK;       // NBUK
    int*   cursor     = bucket_ptr + NBUK;       // NBUK
    int*   row_ptr    = cursor + NBUK;           // NROWPAD
    int*   row_cnt    = row_ptr + NROWPAD;       // NROWPAD
    size_t req = (size_t)((char*)(row_cnt + NROWPAD) - (char*)d_ws);

    if (ws_size < req && ws_size >= (size_t)3 * NELEM * 4) {
        // fallback: round-1 atomic path (needs only 3*NELEM floats)
        float* acc = (float*)d_ws;
        float* Af  = acc + NELEM;
        float* Bf  = Af + NELEM;
        long long st = (long long)NNZ * 64;
        int sb = (int)((st + TPB - 1) / TPB);
        lgcn_init_fb<<<init_blocks, TPB, 0, stream>>>(user_emb, item_emb, acc, Af, Bf);
        lgcn_spmm_fb<<<sb, TPB, 0, stream>>>(edge_row, edge_col, edge_val, Af, Bf);
        lgcn_accum_fb<<<init_blocks, TPB, 0, stream>>>(acc, Bf, Af);
        lgcn_spmm_fb<<<sb, TPB, 0, stream>>>(edge_row, edge_col, edge_val, Bf, Af);
        lgcn_accum_fb<<<init_blocks, TPB, 0, stream>>>(acc, Af, Bf);
        lgcn_spmm_fb<<<sb, TPB, 0, stream>>>(edge_row, edge_col, edge_val, Af, Bf);
        lgcn_accum_fb<<<init_blocks, TPB, 0, stream>>>(acc, Bf, nullptr);
        lgcn_dot_fb<<<dot_blocks, TPB, 0, stream>>>(acc, users, items, out);
        return;
    }

    // init E0 bf16 + zero bucket histogram
    lgcn_init<<<init_blocks, TPB, 0, stream>>>(user_emb, item_emb, A, bucket_cnt);

    // binning: count -> scan -> coarse scatter -> in-LDS exact sort (emits CSR)
    lgcn_bucket_count<<<EB, TPB, 0, stream>>>(edge_row, bucket_cnt);
    lgcn_bucket_scan<<<1, 1024, 0, stream>>>(bucket_cnt, bucket_ptr, cursor);
    lgcn_bucket_scatter<<<EB, TPB, 0, stream>>>(edge_row, edge_col, edge_val, cursor, pairs);
    lgcn_bucket_sort<<<NBUK, TPB, 0, stream>>>(pairs, bucket_ptr, bucket_cnt, row_ptr, row_cnt);

    // layers 1,2 full width (bf16); layer 3 only at sampled rows (f32)
    lgcn_spmm_csr<<<spmm_blocks, TPB, 0, stream>>>(pairs, row_ptr, row_cnt, A, B);
    lgcn_spmm_csr<<<spmm_blocks, TPB, 0, stream>>>(pairs, row_ptr, row_cnt, B, C);
    lgcn_spmm_sampled<<<samp_blocks, TPB, 0, stream>>>(pairs, row_ptr, row_cnt, C,
                                                       users, items, e3);

    // gamma
    lgcn_dot<<<dot_blocks, TPB, 0, stream>>>(user_emb, item_emb, B, C, e3,
                                             users, items, out);
}